// Round 9
// baseline (374.417 us; speedup 1.0000x reference)
//
#include <hip/hip_runtime.h>
#include <hip/hip_bf16.h>

typedef __attribute__((ext_vector_type(8))) short bf16x8;   // 8 bf16 = 4 VGPR MFMA operand
typedef __attribute__((ext_vector_type(4))) float f32x4;    // 16x16 accum
typedef __attribute__((ext_vector_type(16))) float f32x16;  // 32x32 accum
typedef __attribute__((ext_vector_type(4))) unsigned int u32x4;

#define AS3(p)  ((__attribute__((address_space(3))) unsigned int*)(p))
#define AS1C(p) ((const __attribute__((address_space(1))) unsigned int*)(p))

__device__ __forceinline__ ushort f2b(float f){
  __hip_bfloat16 h = __float2bfloat16(f);
  return *reinterpret_cast<ushort*>(&h);
}
__device__ __forceinline__ float b2f(ushort u){
  unsigned int x = ((unsigned int)u) << 16;
  return __uint_as_float(x);
}
// round-to-nearest bf16 pair pack: 2 adds + 1 v_perm (finite values only)
__device__ __forceinline__ unsigned int pack_rn(float lo, float hi){
  unsigned int a = __float_as_uint(lo) + 0x8000u;
  unsigned int b = __float_as_uint(hi) + 0x8000u;
  return __builtin_amdgcn_perm(b, a, 0x07060302u);   // [lo.hi16 | hi.hi16]
}

// dtype sniff over ushorts 0..255 of x — BOTH parities (even words are fp32 low-halves =
// mantissa garbage when data is fp32; odd words alone look like valid bf16!).
__device__ __forceinline__ int sniff_f32(const ushort* __restrict__ x, int flat){
  int l = flat & 63;
  float a = b2f(x[l]),     b = b2f(x[l+64]);
  float c = b2f(x[l+128]), d = b2f(x[l+192]);
  int bad = (!(fabsf(a) < 1e6f)) || (!(fabsf(b) < 1e6f)) ||
            (!(fabsf(c) < 1e6f)) || (!(fabsf(d) < 1e6f));
  return __ballot(bad) != 0ULL;
}

// ---------------- fused prep: x->bf16 (vectorized) + both weight transposes ----------------
__global__ __launch_bounds__(256) void prep(
    const void* __restrict__ x, ushort* __restrict__ xb,
    const void* __restrict__ Wqkv, ushort* __restrict__ WqkvT,
    const void* __restrict__ Wout, ushort* __restrict__ WoutT){
  __shared__ ushort t[32][33];
  const int bid = blockIdx.x, tid = threadIdx.x;
  if (bid < 2048){
    const int isf = sniff_f32((const ushort*)x, tid);
    int i = (bid*256 + tid)*8;             // 2048*256*8 = 4,194,304 = n exactly
    if (isf){
      const float* s = (const float*)x;
      float4 f0 = *(const float4*)(s+i);
      float4 f1 = *(const float4*)(s+i+4);
      u32x4 o;
      o[0] = pack_rn(f0.x, f0.y); o[1] = pack_rn(f0.z, f0.w);
      o[2] = pack_rn(f1.x, f1.y); o[3] = pack_rn(f1.z, f1.w);
      *(u32x4*)(xb+i) = o;
    } else {
      *(u32x4*)(xb+i) = *(const u32x4*)((const ushort*)x + i);
    }
  } else {
    const int isf = sniff_f32((const ushort*)x, tid);
    const void* in; ushort* out; int R, C, bx, by;
    if (bid < 2816){ int q = bid-2048; in = Wqkv; out = WqkvT; R = 512; C = 1536; bx = q%48; by = q/48; }
    else           { int q = bid-2816; in = Wout; out = WoutT; R = 512; C = 512;  bx = q%16; by = q/16; }
    int c0 = bx*32, r0 = by*32;
    int tx = tid&31, ty = tid>>5;
#pragma unroll
    for (int r=0;r<32;r+=8){
      size_t idx = (size_t)(r0+ty+r)*C + c0+tx;
      t[ty+r][tx] = isf ? f2b(((const float*)in)[idx]) : ((const ushort*)in)[idx];
    }
    __syncthreads();
#pragma unroll
    for (int r=0;r<32;r+=8) out[(size_t)(c0+ty+r)*R + r0+tx] = t[tx][ty+r];
  }
}

// ---------------- QKV GEMM (BK=64, swizzled LDS) + rotor-chain RoPE epilogue ----------------
// xb [8192][512] @ WqkvT[1536][512] -> Q,K [bh][4096][64] (Q pre-scaled 0.125*log2e), V [bh][64][4096]
__global__ __launch_bounds__(256, 3) void qkv_rope(
    const ushort* __restrict__ X, const ushort* __restrict__ WT,
    ushort* __restrict__ Q, ushort* __restrict__ Ko, ushort* __restrict__ VT){
  __shared__ __align__(16) ushort Al[128*64];   // 16 KB
  __shared__ __align__(16) ushort Bl[128*64];   // 16 KB
  __shared__ __align__(16) ushort Tl[64*136];   // 17.4 KB V-transpose staging
  const int w = threadIdx.x>>6, lane = threadIdx.x&63;
  const int n0 = blockIdx.x*128, m0 = blockIdx.y*128;
  f32x4 acc[4][4] = {};
  const ushort* Ag = X  + (size_t)m0*512;
  const ushort* Bg = WT + (size_t)n0*512;
  const int srow = lane>>3, sphys = lane&7;     // staging: 8 rows x 8 chunks per wave-instr
  for (int k0=0;k0<512;k0+=64){
#pragma unroll
    for (int tt=0;tt<4;tt++){
      int r = tt*32 + w*8 + srow;
      int lc = sphys ^ (r&7);                   // logical chunk at physical slot
      __builtin_amdgcn_global_load_lds(AS1C(Ag + (size_t)r*512 + k0 + lc*8), AS3(Al + (tt*32+w*8)*64), 16, 0, 0);
      __builtin_amdgcn_global_load_lds(AS1C(Bg + (size_t)r*512 + k0 + lc*8), AS3(Bl + (tt*32+w*8)*64), 16, 0, 0);
    }
    __syncthreads();
    const int mh = (w>>1)*64, nh = (w&1)*64;
#pragma unroll
    for (int kk=0;kk<2;kk++){
      bf16x8 af[4], bf[4];
#pragma unroll
      for (int mt=0;mt<4;mt++){
        int r = mh + mt*16 + (lane&15);
        int pc = (kk*4 + (lane>>4)) ^ (r&7);
        af[mt] = *(const bf16x8*)(Al + r*64 + pc*8);
      }
#pragma unroll
      for (int nt=0;nt<4;nt++){
        int r = nh + nt*16 + (lane&15);
        int pc = (kk*4 + (lane>>4)) ^ (r&7);
        bf[nt] = *(const bf16x8*)(Bl + r*64 + pc*8);
      }
#pragma unroll
      for (int mt=0;mt<4;mt++)
#pragma unroll
        for (int nt=0;nt<4;nt++)
          acc[mt][nt] = __builtin_amdgcn_mfma_f32_16x16x32_bf16(af[mt], bf[nt], acc[mt][nt], 0,0,0);
    }
    __syncthreads();
  }
  const int c = lane & 15;
  if (n0 < 1024){
    const int colbase = n0 + (w&1)*64;
    const int sec = colbase >> 9;              // 0=Q 1=K (uniform per wave)
    const int h = (colbase & 511) >> 6;
    // Q scale folds HD^-0.5 AND log2(e) so flash can use raw v_exp_f32 (exp2)
    const float scale = (sec==0) ? 0.125f*1.44269504089f : 1.0f;
    ushort* Out = (sec==0) ? Q : Ko;
    const int sbase = (m0 & 4095) + (w>>1)*64 + (lane>>4)*4;   // blocks never straddle b
    const int bb = m0 >> 12;
    const size_t obase0 = ((size_t)(bb*8+h)*4096)*64;
    // rotor-chain RoPE: 9 transcendentals + 15 complex mults per freq (vs 48 trans)
#pragma unroll
    for (int nt=0; nt<2; nt++){
      const int d1 = nt*16 + c;
      float wrev = __builtin_amdgcn_exp2f(-0.415241011861f * (float)d1) * 0.159154943092f;
      float fr  = __builtin_amdgcn_fractf((float)sbase * wrev);
      float cm  = __builtin_amdgcn_cosf(fr);
      float sm  = __builtin_amdgcn_sinf(fr);
      float f1  = __builtin_amdgcn_fractf(wrev);
      float c1  = __builtin_amdgcn_cosf(f1);
      float s1  = __builtin_amdgcn_sinf(f1);
      float f16_ = __builtin_amdgcn_fractf(16.0f * wrev);
      float c16 = __builtin_amdgcn_cosf(f16_);
      float s16 = __builtin_amdgcn_sinf(f16_);
#pragma unroll
      for (int mt=0;mt<4;mt++){
        float cr = cm, sr = sm;
#pragma unroll
        for (int reg=0;reg<4;reg++){
          int srw = sbase + mt*16 + reg;
          size_t obase = obase0 + (size_t)srw*64;
          float v1 = acc[mt][nt][reg], v2 = acc[mt][nt+2][reg];
          Out[obase + d1]      = f2b(scale*(v1*cr - v2*sr));
          Out[obase + d1 + 32] = f2b(scale*(v2*cr + v1*sr));
          float cn = cr*c1 - sr*s1;
          sr = cr*s1 + sr*c1;
          cr = cn;
        }
        float cn = cm*c16 - sm*s16;
        sm = cm*s16 + sm*c16;
        cm = cn;
      }
    }
  } else {
    // V path: stage [64 d][128 s] tile in LDS, then 256B-contiguous global stores
    const int M = w>>1, P = w&1;
    const int bb = m0>>12, s0 = m0&4095;
    const int dR = threadIdx.x>>4, sj = threadIdx.x&15;
#pragma unroll
    for (int ph=0; ph<2; ph++){
      if (P == ph){
#pragma unroll
        for (int mt=0;mt<4;mt++)
#pragma unroll
          for (int nt=0;nt<4;nt++){
            ushort4 pk;
            pk.x = f2b(acc[mt][nt][0]);
            pk.y = f2b(acc[mt][nt][1]);
            pk.z = f2b(acc[mt][nt][2]);
            pk.w = f2b(acc[mt][nt][3]);
            *(ushort4*)&Tl[(nt*16+c)*136 + M*64 + mt*16 + (lane>>4)*4] = pk;
          }
      }
      __syncthreads();
      const int hh = ((n0 + ph*64) & 511) >> 6;
      ushort* baseV = VT + ((size_t)(bb*8+hh)*64)*4096 + s0;
#pragma unroll
      for (int pass=0; pass<4; pass++){
        int d = pass*16 + dR;
        *(u32x4*)(baseV + (size_t)d*4096 + sj*8) = *(const u32x4*)&Tl[d*136 + sj*8];
      }
      __syncthreads();
    }
  }
}

// one flash tile with STATIC LDS buffer bases (KB/VB compile-time) — loop-invariant ds addresses
#define FLASH_TILE(KB, VB) do{                                                   \
    const int k0_ = j*64;                                                        \
    const bool dm_ = (k0_ + 63) > (q0 + w*32);                                   \
    _Pragma("unroll")                                                            \
    for (int nt=0;nt<2;nt++){                                                    \
      f32x16 s_ = {};                                                            \
      _Pragma("unroll")                                                          \
      for (int kt=0;kt<4;kt++){                                                  \
        int kr = nt*32+ln;                                                       \
        int p = (kt*2+half) ^ (kr&7);                                            \
        bf16x8 kf = *(const bf16x8*)((KB) + kr*64 + p*8);                        \
        s_ = __builtin_amdgcn_mfma_f32_32x32x16_bf16(kf, qf[kt], s_, 0,0,0);     \
      }                                                                          \
      float pv[16];                                                              \
      if (dm_){                                                                  \
        const int thr = qg - (k0_ + nt*32 + 4*half);                             \
        _Pragma("unroll")                                                        \
        for (int r=0;r<16;r++)                                                   \
          pv[r] = ((8*(r>>2)+(r&3)) > thr) ? 0.0f : __builtin_amdgcn_exp2f(s_[r]); \
      } else {                                                                   \
        _Pragma("unroll")                                                        \
        for (int r=0;r<16;r++) pv[r] = __builtin_amdgcn_exp2f(s_[r]);            \
      }                                                                          \
      unsigned int qk[8];                                                        \
      _Pragma("unroll")                                                          \
      for (int qd=0;qd<4;qd++){                                                  \
        lsum += (pv[4*qd]+pv[4*qd+1]) + (pv[4*qd+2]+pv[4*qd+3]);                 \
        qk[2*qd]   = pack_rn(pv[4*qd],   pv[4*qd+1]);                            \
        qk[2*qd+1] = pack_rn(pv[4*qd+2], pv[4*qd+3]);                            \
      }                                                                          \
      _Pragma("unroll")                                                          \
      for (int khi=0;khi<2;khi++){                                               \
        union { unsigned int u[4]; bf16x8 v; } pf;                               \
        pf.u[0] = qk[khi*4+0]; pf.u[1] = qk[khi*4+1];                            \
        pf.u[2] = qk[khi*4+2]; pf.u[3] = qk[khi*4+3];                            \
        const int c0_ = nt*4 + khi*2;                                            \
        _Pragma("unroll")                                                        \
        for (int dt=0;dt<2;dt++){                                                \
          int vr = dt*32+ln;                                                     \
          int pc0 = c0_ ^ (vr&7);                                                \
          int pc1 = (c0_+1) ^ (vr&7);                                            \
          union { unsigned int u[4]; bf16x8 v; } vf;                             \
          *(uint2*)&vf.u[0] = *(const uint2*)((VB) + vr*64 + pc0*8 + half*4);    \
          *(uint2*)&vf.u[2] = *(const uint2*)((VB) + vr*64 + pc1*8 + half*4);    \
          oacc[dt] = __builtin_amdgcn_mfma_f32_32x32x16_bf16(pf.v, vf.v, oacc[dt], 0,0,0); \
        }                                                                        \
      }                                                                          \
    }                                                                            \
  }while(0)

// ---------------- causal flash attention + fused split-pair combine (atomic handshake) ----------------
// Q,K: [bh][4096][64] bf16 (Q pre-scaled 0.125*log2e). V: [bh][64][4096] bf16.
__global__ __launch_bounds__(256, 4) void flash_attn(
    const ushort* __restrict__ Q, const ushort* __restrict__ K,
    const ushort* __restrict__ V, ushort* __restrict__ O,
    ushort* __restrict__ Opart, float* __restrict__ Lpart, int* __restrict__ cnt){
  __shared__ __align__(16) ushort Kl[2][64*64];   // 2 x 8 KB
  __shared__ __align__(16) ushort Vl[2][64*64];   // 2 x 8 KB
  const int w = threadIdx.x>>6, lane = threadIdx.x&63;
  const int ln = lane&31, half = lane>>5;
  // XCD-pinned: round-robin z%8 -> XCD => each XCD serves 2 bh (2MB K/V < 4MB L2)
  const int z = blockIdx.x;
  const int bh = (z&7)*2 + ((z>>3)&1);
  const int t = z>>4;                        // 0..47, heavy chunks first
  int qi, jlo, jhi, mode, slot = 0;
  if (t < 16){ qi = 15 - t; jlo = 0; jhi = 2*qi+1; mode = 0; }
  else {
    int u = t - 16; qi = 31 - (u>>1); int hf = u&1;
    jlo = hf ? (qi+1) : 0; jhi = hf ? (2*qi+1) : qi; mode = 1;   // balanced halves of 2qi+2 tiles
    slot = (bh*16 + (qi-16))*2 + hf;
  }
  const int q0 = qi*128;
  const int qg = q0 + w*32 + ln;
  const ushort* Qb = Q + (size_t)bh*4096*64;
  const ushort* Kb = K + (size_t)bh*4096*64;
  const ushort* Vb = V + (size_t)bh*4096*64;
  bf16x8 qf[4];
#pragma unroll
  for (int kt=0;kt<4;kt++)
    qf[kt] = *(const bf16x8*)(Qb + (size_t)qg*64 + kt*16 + half*8);
  f32x16 oacc[2] = {};
  float lsum = 0.0f;
  const int r8 = lane>>3, sl = lane&7;
  auto stage = [&](int jj, int b){
    const int k0 = jj*64;
    ushort* Kd = &Kl[b][0];
    ushort* Vd = &Vl[b][0];
#pragma unroll
    for (int tt=0;tt<2;tt++){
      int rr = w*16 + tt*8 + r8;
      int lc = sl ^ (rr&7);
      __builtin_amdgcn_global_load_lds(AS1C(Kb + (size_t)(k0+rr)*64 + lc*8),
                                       AS3(Kd + (w*16+tt*8)*64), 16, 0, 0);
      __builtin_amdgcn_global_load_lds(AS1C(Vb + (size_t)rr*4096 + k0 + lc*8),
                                       AS3(Vd + (w*16+tt*8)*64), 16, 0, 0);
    }
  };
  stage(jlo, 0);
  int j = jlo;
  for (;;){
    __syncthreads();                 // buf0 landed (issued one full tile-compute ago)
    if (j < jhi) stage(j+1, 1);      // prefetch overlaps compute below
    FLASH_TILE(&Kl[0][0], &Vl[0][0]);
    if (++j > jhi) break;
    __syncthreads();                 // buf1 landed
    if (j < jhi) stage(j+1, 0);
    FLASH_TILE(&Kl[1][0], &Vl[1][0]);
    if (++j > jhi) break;
  }
  const int b = bh>>3, h = bh&7;
  if (mode == 0){
    float linv = 1.0f / (lsum + __shfl_xor(lsum, 32));
#pragma unroll
    for (int reg=0;reg<16;reg++){
      int qlocal = (reg&3) + 8*(reg>>2) + 4*half;
      float li = __shfl(linv, qlocal);
      int srw = q0 + w*32 + qlocal;
#pragma unroll
      for (int dt=0;dt<2;dt++)
        O[((size_t)(b*4096+srw))*512 + h*64 + dt*32 + ln] = f2b(oacc[dt][reg]*li);
    }
  } else {
    ushort* Ob = Opart + (size_t)slot*8192;
#pragma unroll
    for (int reg=0;reg<16;reg++){
      int qlocal = (reg&3) + 8*(reg>>2) + 4*half;
      int r = w*32 + qlocal;
#pragma unroll
      for (int dt=0;dt<2;dt++)
        Ob[r*64 + dt*32 + ln] = f2b(oacc[dt][reg]);
    }
    float lrow = lsum + __shfl_xor(lsum, 32);
    if (half == 0) Lpart[slot*128 + w*32 + ln] = lrow;
    // handshake: second finisher of the pair combines + writes O
    __threadfence();                 // release our partial (device scope)
    __syncthreads();                 // all threads' stores+fences before the signal
    __shared__ int oldv;
    if (threadIdx.x == 0)
      oldv = __hip_atomic_fetch_add(&cnt[slot>>1], 1, __ATOMIC_ACQ_REL, __HIP_MEMORY_SCOPE_AGENT);
    __syncthreads();
    if (oldv == 1){
      __threadfence();               // acquire partner's partial
      const ushort* O1 = Opart + (size_t)(slot & ~1)*8192;
      const ushort* O2 = O1 + 8192;
      const float*  L1 = Lpart + (slot & ~1)*128;
      const float*  L2 = L1 + 128;
      const int r0 = threadIdx.x>>3, c8 = (threadIdx.x&7)*8;
#pragma unroll
      for (int it=0; it<4; it++){
        int r = r0 + it*32;
        float li = 1.0f / (L1[r] + L2[r]);
        u32x4 a  = *(const u32x4*)(O1 + r*64 + c8);
        u32x4 b2 = *(const u32x4*)(O2 + r*64 + c8);
        u32x4 o;
#pragma unroll
        for (int e=0;e<4;e++){
          float alo = __uint_as_float(a[e]<<16),  ahi = __uint_as_float(a[e]&0xffff0000u);
          float blo = __uint_as_float(b2[e]<<16), bhi = __uint_as_float(b2[e]&0xffff0000u);
          o[e] = pack_rn((alo+blo)*li, (ahi+bhi)*li);
        }
        *(u32x4*)(O + ((size_t)(b*4096 + q0 + r))*512 + h*64 + c8) = o;
      }
    }
  }
}

// ---------------- output projection (64x128 tiles, BK=64, swizzled LDS; 512 blocks) ----------------
__global__ __launch_bounds__(256, 4) void out_proj(
    const ushort* __restrict__ A, const ushort* __restrict__ WT,
    void* __restrict__ Out, const ushort* __restrict__ xs){
  __shared__ __align__(16) ushort Al[64*64];    // 8 KB
  __shared__ __align__(16) ushort Bl[128*64];   // 16 KB
  const int isf = sniff_f32(xs, threadIdx.x);
  const int w = threadIdx.x>>6, lane = threadIdx.x&63;
  const int n0 = blockIdx.x*128, m0 = blockIdx.y*64;
  f32x4 acc[2][4] = {};
  const ushort* Ag = A  + (size_t)m0*512;
  const ushort* Bg = WT + (size_t)n0*512;
  const int srow = lane>>3, sphys = lane&7;
  for (int k0=0;k0<512;k0+=64){
#pragma unroll
    for (int tt=0;tt<4;tt++){
      int r = tt*32 + w*8 + srow;
      int lc = sphys ^ (r&7);
      __builtin_amdgcn_global_load_lds(AS1C(Bg + (size_t)r*512 + k0 + lc*8), AS3(Bl + (tt*32+w*8)*64), 16, 0, 0);
      if (tt < 2)
        __builtin_amdgcn_global_load_lds(AS1C(Ag + (size_t)r*512 + k0 + lc*8), AS3(Al + (tt*32+w*8)*64), 16, 0, 0);
    }
    __syncthreads();
    const int mh = (w>>1)*32, nh = (w&1)*64;
#pragma unroll
    for (int kk=0;kk<2;kk++){
      bf16x8 af[2], bf[4];
#pragma unroll
      for (int mt=0;mt<2;mt++){
        int r = mh + mt*16 + (lane&15);
        int pc = (kk*4 + (lane>>4)) ^ (r&7);
        af[mt] = *(const bf16x8*)(Al + r*64 + pc*8);
      }
#pragma unroll
      for (int nt=0;nt<4;nt++){
        int r = nh + nt*16 + (lane&15);
        int pc = (kk*4 + (lane>>4)) ^ (r&7);
        bf[nt] = *(const bf16x8*)(Bl + r*64 + pc*8);
      }
#pragma unroll
      for (int mt=0;mt<2;mt++)
#pragma unroll
        for (int nt=0;nt<4;nt++)
          acc[mt][nt] = __builtin_amdgcn_mfma_f32_16x16x32_bf16(af[mt], bf[nt], acc[mt][nt], 0,0,0);
    }
    __syncthreads();
  }
  const int c = lane&15;
  const int rbase = m0 + (w>>1)*32 + (lane>>4)*4;
  const int cb = n0 + (w&1)*64;
#pragma unroll
  for (int mt=0;mt<2;mt++)
#pragma unroll
    for (int nt=0;nt<4;nt++)
#pragma unroll
      for (int reg=0;reg<4;reg++){
        int rg = rbase + mt*16 + reg;
        size_t idx = (size_t)rg*512 + cb + nt*16 + c;
        float v = acc[mt][nt][reg];
        if (isf) ((float*)Out)[idx] = v;
        else     ((ushort*)Out)[idx] = f2b(v);
      }
}

// ---------------- launcher ----------------
extern "C" void kernel_launch(void* const* d_in, const int* in_sizes, int n_in,
                              void* d_out, int out_size, void* d_ws, size_t ws_size,
                              hipStream_t stream){
  const void* x    = d_in[0];   // [2,4096,512]
  const void* Wqkv = d_in[1];   // [512,1536]
  const void* Wout = d_in[2];   // [512,512]
  // d_in[3] = attention_mask (causal by construction; applied analytically)
  char* ws = (char*)d_ws;
  int*    cnt   = (int*)   (ws);                 //     1,024  (split-pair counters)
  float*  Lpart = (float*) (ws + 4096);          //   524,288
  ushort* WqkvT = (ushort*)(ws + 1052672);       // 1,572,864
  ushort* WoutT = (ushort*)(ws + 2625536);       //   524,288
  ushort* xb    = (ushort*)(ws + 3149824);       // 8,388,608  (reused as Opart after qkv_rope)
  ushort* Qw    = (ushort*)(ws + 11538432);      // 8,388,608
  ushort* Kw    = (ushort*)(ws + 19927040);      // 8,388,608
  ushort* Vw    = (ushort*)(ws + 28315648);      // 8,388,608 (transposed per head)
  ushort* Ow    = (ushort*)(ws + 36704256);      // 8,388,608 -> total 45,092,864 B
  ushort* Opart = xb;

  hipMemsetAsync(cnt, 0, 1024, stream);
  prep     <<<dim3(3072),  dim3(256), 0, stream>>>(x, xb, Wqkv, WqkvT, Wout, WoutT);
  qkv_rope <<<dim3(12,64), dim3(256), 0, stream>>>(xb, WqkvT, Qw, Kw, Vw);
  flash_attn<<<dim3(768),  dim3(256), 0, stream>>>(Qw, Kw, Vw, Ow, Opart, Lpart, cnt);
  out_proj <<<dim3(4,128), dim3(256), 0, stream>>>(Ow, WoutT, d_out, (const ushort*)x);
}

// Round 10
// 260.843 us; speedup vs baseline: 1.4354x; 1.4354x over previous
//
#include <hip/hip_runtime.h>
#include <hip/hip_bf16.h>

typedef __attribute__((ext_vector_type(8))) short bf16x8;   // 8 bf16 = 4 VGPR MFMA operand
typedef __attribute__((ext_vector_type(4))) float f32x4;    // 16x16 accum
typedef __attribute__((ext_vector_type(16))) float f32x16;  // 32x32 accum
typedef __attribute__((ext_vector_type(4))) unsigned int u32x4;

#define AS3(p)  ((__attribute__((address_space(3))) unsigned int*)(p))
#define AS1C(p) ((const __attribute__((address_space(1))) unsigned int*)(p))

__device__ __forceinline__ ushort f2b(float f){
  __hip_bfloat16 h = __float2bfloat16(f);
  return *reinterpret_cast<ushort*>(&h);
}
__device__ __forceinline__ float b2f(ushort u){
  unsigned int x = ((unsigned int)u) << 16;
  return __uint_as_float(x);
}
// round-to-nearest bf16 pair pack: 2 adds + 1 v_perm (finite values only)
__device__ __forceinline__ unsigned int pack_rn(float lo, float hi){
  unsigned int a = __float_as_uint(lo) + 0x8000u;
  unsigned int b = __float_as_uint(hi) + 0x8000u;
  return __builtin_amdgcn_perm(b, a, 0x07060302u);   // [lo.hi16 | hi.hi16]
}

// dtype sniff over ushorts 0..255 of x — BOTH parities (even words are fp32 low-halves =
// mantissa garbage when data is fp32; odd words alone look like valid bf16!).
__device__ __forceinline__ int sniff_f32(const ushort* __restrict__ x, int flat){
  int l = flat & 63;
  float a = b2f(x[l]),     b = b2f(x[l+64]);
  float c = b2f(x[l+128]), d = b2f(x[l+192]);
  int bad = (!(fabsf(a) < 1e6f)) || (!(fabsf(b) < 1e6f)) ||
            (!(fabsf(c) < 1e6f)) || (!(fabsf(d) < 1e6f));
  return __ballot(bad) != 0ULL;
}

// ---------------- fused prep: x->bf16 (vectorized) + both weight transposes ----------------
__global__ __launch_bounds__(256) void prep(
    const void* __restrict__ x, ushort* __restrict__ xb,
    const void* __restrict__ Wqkv, ushort* __restrict__ WqkvT,
    const void* __restrict__ Wout, ushort* __restrict__ WoutT){
  __shared__ ushort t[32][33];
  const int bid = blockIdx.x, tid = threadIdx.x;
  if (bid < 2048){
    const int isf = sniff_f32((const ushort*)x, tid);
    int i = (bid*256 + tid)*8;             // 2048*256*8 = 4,194,304 = n exactly
    if (isf){
      const float* s = (const float*)x;
      float4 f0 = *(const float4*)(s+i);
      float4 f1 = *(const float4*)(s+i+4);
      u32x4 o;
      o[0] = pack_rn(f0.x, f0.y); o[1] = pack_rn(f0.z, f0.w);
      o[2] = pack_rn(f1.x, f1.y); o[3] = pack_rn(f1.z, f1.w);
      *(u32x4*)(xb+i) = o;
    } else {
      *(u32x4*)(xb+i) = *(const u32x4*)((const ushort*)x + i);
    }
  } else {
    const int isf = sniff_f32((const ushort*)x, tid);
    const void* in; ushort* out; int R, C, bx, by;
    if (bid < 2816){ int q = bid-2048; in = Wqkv; out = WqkvT; R = 512; C = 1536; bx = q%48; by = q/48; }
    else           { int q = bid-2816; in = Wout; out = WoutT; R = 512; C = 512;  bx = q%16; by = q/16; }
    int c0 = bx*32, r0 = by*32;
    int tx = tid&31, ty = tid>>5;
#pragma unroll
    for (int r=0;r<32;r+=8){
      size_t idx = (size_t)(r0+ty+r)*C + c0+tx;
      t[ty+r][tx] = isf ? f2b(((const float*)in)[idx]) : ((const ushort*)in)[idx];
    }
    __syncthreads();
#pragma unroll
    for (int r=0;r<32;r+=8) out[(size_t)(c0+ty+r)*R + r0+tx] = t[tx][ty+r];
  }
}

// ---------------- QKV GEMM (BK=64, swizzled LDS) + rotor-chain RoPE epilogue ----------------
// xb [8192][512] @ WqkvT[1536][512] -> Q,K [bh][4096][64] (Q pre-scaled 0.125*log2e), V [bh][64][4096]
__global__ __launch_bounds__(256, 3) void qkv_rope(
    const ushort* __restrict__ X, const ushort* __restrict__ WT,
    ushort* __restrict__ Q, ushort* __restrict__ Ko, ushort* __restrict__ VT){
  __shared__ __align__(16) ushort Al[128*64];   // 16 KB
  __shared__ __align__(16) ushort Bl[128*64];   // 16 KB
  __shared__ __align__(16) ushort Tl[64*136];   // 17.4 KB V-transpose staging
  const int w = threadIdx.x>>6, lane = threadIdx.x&63;
  const int n0 = blockIdx.x*128, m0 = blockIdx.y*128;
  f32x4 acc[4][4] = {};
  const ushort* Ag = X  + (size_t)m0*512;
  const ushort* Bg = WT + (size_t)n0*512;
  const int srow = lane>>3, sphys = lane&7;     // staging: 8 rows x 8 chunks per wave-instr
  for (int k0=0;k0<512;k0+=64){
#pragma unroll
    for (int tt=0;tt<4;tt++){
      int r = tt*32 + w*8 + srow;
      int lc = sphys ^ (r&7);                   // logical chunk at physical slot
      __builtin_amdgcn_global_load_lds(AS1C(Ag + (size_t)r*512 + k0 + lc*8), AS3(Al + (tt*32+w*8)*64), 16, 0, 0);
      __builtin_amdgcn_global_load_lds(AS1C(Bg + (size_t)r*512 + k0 + lc*8), AS3(Bl + (tt*32+w*8)*64), 16, 0, 0);
    }
    __syncthreads();
    const int mh = (w>>1)*64, nh = (w&1)*64;
#pragma unroll
    for (int kk=0;kk<2;kk++){
      bf16x8 af[4], bf[4];
#pragma unroll
      for (int mt=0;mt<4;mt++){
        int r = mh + mt*16 + (lane&15);
        int pc = (kk*4 + (lane>>4)) ^ (r&7);
        af[mt] = *(const bf16x8*)(Al + r*64 + pc*8);
      }
#pragma unroll
      for (int nt=0;nt<4;nt++){
        int r = nh + nt*16 + (lane&15);
        int pc = (kk*4 + (lane>>4)) ^ (r&7);
        bf[nt] = *(const bf16x8*)(Bl + r*64 + pc*8);
      }
#pragma unroll
      for (int mt=0;mt<4;mt++)
#pragma unroll
        for (int nt=0;nt<4;nt++)
          acc[mt][nt] = __builtin_amdgcn_mfma_f32_16x16x32_bf16(af[mt], bf[nt], acc[mt][nt], 0,0,0);
    }
    __syncthreads();
  }
  const int c = lane & 15;
  if (n0 < 1024){
    const int colbase = n0 + (w&1)*64;
    const int sec = colbase >> 9;              // 0=Q 1=K (uniform per wave)
    const int h = (colbase & 511) >> 6;
    // Q scale folds HD^-0.5 AND log2(e) so flash can use raw v_exp_f32 (exp2)
    const float scale = (sec==0) ? 0.125f*1.44269504089f : 1.0f;
    ushort* Out = (sec==0) ? Q : Ko;
    const int sbase = (m0 & 4095) + (w>>1)*64 + (lane>>4)*4;   // blocks never straddle b
    const int bb = m0 >> 12;
    const size_t obase0 = ((size_t)(bb*8+h)*4096)*64;
    // rotor-chain RoPE: 9 transcendentals + 15 complex mults per freq (vs 48 trans)
#pragma unroll
    for (int nt=0; nt<2; nt++){
      const int d1 = nt*16 + c;
      float wrev = __builtin_amdgcn_exp2f(-0.415241011861f * (float)d1) * 0.159154943092f;
      float fr  = __builtin_amdgcn_fractf((float)sbase * wrev);
      float cm  = __builtin_amdgcn_cosf(fr);
      float sm  = __builtin_amdgcn_sinf(fr);
      float f1  = __builtin_amdgcn_fractf(wrev);
      float c1  = __builtin_amdgcn_cosf(f1);
      float s1  = __builtin_amdgcn_sinf(f1);
      float f16_ = __builtin_amdgcn_fractf(16.0f * wrev);
      float c16 = __builtin_amdgcn_cosf(f16_);
      float s16 = __builtin_amdgcn_sinf(f16_);
#pragma unroll
      for (int mt=0;mt<4;mt++){
        float cr = cm, sr = sm;
#pragma unroll
        for (int reg=0;reg<4;reg++){
          int srw = sbase + mt*16 + reg;
          size_t obase = obase0 + (size_t)srw*64;
          float v1 = acc[mt][nt][reg], v2 = acc[mt][nt+2][reg];
          Out[obase + d1]      = f2b(scale*(v1*cr - v2*sr));
          Out[obase + d1 + 32] = f2b(scale*(v2*cr + v1*sr));
          float cn = cr*c1 - sr*s1;
          sr = cr*s1 + sr*c1;
          cr = cn;
        }
        float cn = cm*c16 - sm*s16;
        sm = cm*s16 + sm*c16;
        cm = cn;
      }
    }
  } else {
    // V path: stage [64 d][128 s] tile in LDS, then 256B-contiguous global stores
    const int M = w>>1, P = w&1;
    const int bb = m0>>12, s0 = m0&4095;
    const int dR = threadIdx.x>>4, sj = threadIdx.x&15;
#pragma unroll
    for (int ph=0; ph<2; ph++){
      if (P == ph){
#pragma unroll
        for (int mt=0;mt<4;mt++)
#pragma unroll
          for (int nt=0;nt<4;nt++){
            ushort4 pk;
            pk.x = f2b(acc[mt][nt][0]);
            pk.y = f2b(acc[mt][nt][1]);
            pk.z = f2b(acc[mt][nt][2]);
            pk.w = f2b(acc[mt][nt][3]);
            *(ushort4*)&Tl[(nt*16+c)*136 + M*64 + mt*16 + (lane>>4)*4] = pk;
          }
      }
      __syncthreads();
      const int hh = ((n0 + ph*64) & 511) >> 6;
      ushort* baseV = VT + ((size_t)(bb*8+hh)*64)*4096 + s0;
#pragma unroll
      for (int pass=0; pass<4; pass++){
        int d = pass*16 + dR;
        *(u32x4*)(baseV + (size_t)d*4096 + sj*8) = *(const u32x4*)&Tl[d*136 + sj*8];
      }
      __syncthreads();
    }
  }
}

// one flash tile with STATIC LDS buffer bases (KB/VB compile-time) — loop-invariant ds addresses
#define FLASH_TILE(KB, VB) do{                                                   \
    const int k0_ = j*64;                                                        \
    const bool dm_ = (k0_ + 63) > (q0 + w*32);                                   \
    _Pragma("unroll")                                                            \
    for (int nt=0;nt<2;nt++){                                                    \
      f32x16 s_ = {};                                                            \
      _Pragma("unroll")                                                          \
      for (int kt=0;kt<4;kt++){                                                  \
        int kr = nt*32+ln;                                                       \
        int p = (kt*2+half) ^ (kr&7);                                            \
        bf16x8 kf = *(const bf16x8*)((KB) + kr*64 + p*8);                        \
        s_ = __builtin_amdgcn_mfma_f32_32x32x16_bf16(kf, qf[kt], s_, 0,0,0);     \
      }                                                                          \
      float pv[16];                                                              \
      if (dm_){                                                                  \
        const int thr = qg - (k0_ + nt*32 + 4*half);                             \
        _Pragma("unroll")                                                        \
        for (int r=0;r<16;r++)                                                   \
          pv[r] = ((8*(r>>2)+(r&3)) > thr) ? 0.0f : __builtin_amdgcn_exp2f(s_[r]); \
      } else {                                                                   \
        _Pragma("unroll")                                                        \
        for (int r=0;r<16;r++) pv[r] = __builtin_amdgcn_exp2f(s_[r]);            \
      }                                                                          \
      unsigned int qk[8];                                                        \
      _Pragma("unroll")                                                          \
      for (int qd=0;qd<4;qd++){                                                  \
        lsum += (pv[4*qd]+pv[4*qd+1]) + (pv[4*qd+2]+pv[4*qd+3]);                 \
        qk[2*qd]   = pack_rn(pv[4*qd],   pv[4*qd+1]);                            \
        qk[2*qd+1] = pack_rn(pv[4*qd+2], pv[4*qd+3]);                            \
      }                                                                          \
      _Pragma("unroll")                                                          \
      for (int khi=0;khi<2;khi++){                                               \
        union { unsigned int u[4]; bf16x8 v; } pf;                               \
        pf.u[0] = qk[khi*4+0]; pf.u[1] = qk[khi*4+1];                            \
        pf.u[2] = qk[khi*4+2]; pf.u[3] = qk[khi*4+3];                            \
        const int c0_ = nt*4 + khi*2;                                            \
        _Pragma("unroll")                                                        \
        for (int dt=0;dt<2;dt++){                                                \
          int vr = dt*32+ln;                                                     \
          int pc0 = c0_ ^ (vr&7);                                                \
          int pc1 = (c0_+1) ^ (vr&7);                                            \
          union { unsigned int u[4]; bf16x8 v; } vf;                             \
          *(uint2*)&vf.u[0] = *(const uint2*)((VB) + vr*64 + pc0*8 + half*4);    \
          *(uint2*)&vf.u[2] = *(const uint2*)((VB) + vr*64 + pc1*8 + half*4);    \
          oacc[dt] = __builtin_amdgcn_mfma_f32_32x32x16_bf16(pf.v, vf.v, oacc[dt], 0,0,0); \
        }                                                                        \
      }                                                                          \
    }                                                                            \
  }while(0)

// ---------------- causal flash attention: 64-k tiles, static dbuf prefetch, permuted-k PV ----------------
// NO device-scope fences/atomics here (R9 lesson: agent fences = per-XCD L2 flush, 2x regression).
__global__ __launch_bounds__(256, 4) void flash_attn(
    const ushort* __restrict__ Q, const ushort* __restrict__ K,
    const ushort* __restrict__ V, ushort* __restrict__ O,
    ushort* __restrict__ Opart, float* __restrict__ Lpart){
  __shared__ __align__(16) ushort Kl[2][64*64];   // 2 x 8 KB
  __shared__ __align__(16) ushort Vl[2][64*64];   // 2 x 8 KB
  const int w = threadIdx.x>>6, lane = threadIdx.x&63;
  const int ln = lane&31, half = lane>>5;
  // XCD-pinned: round-robin z%8 -> XCD => each XCD serves 2 bh (2MB K/V < 4MB L2)
  const int z = blockIdx.x;
  const int bh = (z&7)*2 + ((z>>3)&1);
  const int t = z>>4;                        // 0..47, heavy chunks first
  int qi, jlo, jhi, mode, slot = 0;
  if (t < 16){ qi = 15 - t; jlo = 0; jhi = 2*qi+1; mode = 0; }
  else {
    int u = t - 16; qi = 31 - (u>>1); int hf = u&1;
    jlo = hf ? (qi+1) : 0; jhi = hf ? (2*qi+1) : qi; mode = 1;   // balanced halves of 2qi+2 tiles
    slot = (bh*16 + (qi-16))*2 + hf;
  }
  const int q0 = qi*128;
  const int qg = q0 + w*32 + ln;
  const ushort* Qb = Q + (size_t)bh*4096*64;
  const ushort* Kb = K + (size_t)bh*4096*64;
  const ushort* Vb = V + (size_t)bh*4096*64;
  bf16x8 qf[4];
#pragma unroll
  for (int kt=0;kt<4;kt++)
    qf[kt] = *(const bf16x8*)(Qb + (size_t)qg*64 + kt*16 + half*8);
  f32x16 oacc[2] = {};
  float lsum = 0.0f;
  const int r8 = lane>>3, sl = lane&7;
  auto stage = [&](int jj, int b){
    const int k0 = jj*64;
    ushort* Kd = &Kl[b][0];
    ushort* Vd = &Vl[b][0];
#pragma unroll
    for (int tt=0;tt<2;tt++){
      int rr = w*16 + tt*8 + r8;
      int lc = sl ^ (rr&7);
      __builtin_amdgcn_global_load_lds(AS1C(Kb + (size_t)(k0+rr)*64 + lc*8),
                                       AS3(Kd + (w*16+tt*8)*64), 16, 0, 0);
      __builtin_amdgcn_global_load_lds(AS1C(Vb + (size_t)rr*4096 + k0 + lc*8),
                                       AS3(Vd + (w*16+tt*8)*64), 16, 0, 0);
    }
  };
  stage(jlo, 0);
  int j = jlo;
  for (;;){
    __syncthreads();                 // buf0 landed (issued one full tile-compute ago)
    if (j < jhi) stage(j+1, 1);      // prefetch overlaps compute below
    FLASH_TILE(&Kl[0][0], &Vl[0][0]);
    if (++j > jhi) break;
    __syncthreads();                 // buf1 landed
    if (j < jhi) stage(j+1, 0);
    FLASH_TILE(&Kl[1][0], &Vl[1][0]);
    if (++j > jhi) break;
  }
  const int b = bh>>3, h = bh&7;
  if (mode == 0){
    float linv = 1.0f / (lsum + __shfl_xor(lsum, 32));
#pragma unroll
    for (int reg=0;reg<16;reg++){
      int qlocal = (reg&3) + 8*(reg>>2) + 4*half;
      float li = __shfl(linv, qlocal);
      int srw = q0 + w*32 + qlocal;
#pragma unroll
      for (int dt=0;dt<2;dt++)
        O[((size_t)(b*4096+srw))*512 + h*64 + dt*32 + ln] = f2b(oacc[dt][reg]*li);
    }
  } else {
    ushort* Ob = Opart + (size_t)slot*8192;
#pragma unroll
    for (int reg=0;reg<16;reg++){
      int qlocal = (reg&3) + 8*(reg>>2) + 4*half;
      int r = w*32 + qlocal;
#pragma unroll
      for (int dt=0;dt<2;dt++)
        Ob[r*64 + dt*32 + ln] = f2b(oacc[dt][reg]);
    }
    float lrow = lsum + __shfl_xor(lsum, 32);
    if (half == 0) Lpart[slot*128 + w*32 + ln] = lrow;
  }
}

// ---------------- combine split partials -> O rows for qtiles 16..31 (vectorized) ----------------
__global__ __launch_bounds__(256) void combine(
    const ushort* __restrict__ Opart, const float* __restrict__ Lpart,
    ushort* __restrict__ O){
  const int qq = blockIdx.x;        // 0..15 -> qi = 16+qq
  const int bh = blockIdx.y;
  const int slot0 = (bh*16 + qq)*2;
  const ushort* O1 = Opart + (size_t)slot0*8192;
  const ushort* O2 = O1 + 8192;
  const float*  L1 = Lpart + slot0*128;
  const float*  L2 = L1 + 128;
  const int b = bh>>3, h = bh&7;
  const int s0 = (16+qq)*128;
  const int r0 = threadIdx.x>>3, c8 = (threadIdx.x&7)*8;
#pragma unroll
  for (int it=0; it<4; it++){
    int r = r0 + it*32;
    float li = 1.0f / (L1[r] + L2[r]);
    u32x4 a  = *(const u32x4*)(O1 + r*64 + c8);
    u32x4 b2 = *(const u32x4*)(O2 + r*64 + c8);
    u32x4 o;
#pragma unroll
    for (int e=0;e<4;e++){
      float alo = __uint_as_float(a[e]<<16),  ahi = __uint_as_float(a[e]&0xffff0000u);
      float blo = __uint_as_float(b2[e]<<16), bhi = __uint_as_float(b2[e]&0xffff0000u);
      o[e] = pack_rn((alo+blo)*li, (ahi+bhi)*li);
    }
    *(u32x4*)(O + ((size_t)(b*4096 + s0 + r))*512 + h*64 + c8) = o;
  }
}

// ---------------- output projection (64x128 tiles, BK=64, swizzled LDS; 512 blocks) ----------------
__global__ __launch_bounds__(256, 4) void out_proj(
    const ushort* __restrict__ A, const ushort* __restrict__ WT,
    void* __restrict__ Out, const ushort* __restrict__ xs){
  __shared__ __align__(16) ushort Al[64*64];    // 8 KB
  __shared__ __align__(16) ushort Bl[128*64];   // 16 KB
  const int isf = sniff_f32(xs, threadIdx.x);
  const int w = threadIdx.x>>6, lane = threadIdx.x&63;
  const int n0 = blockIdx.x*128, m0 = blockIdx.y*64;
  f32x4 acc[2][4] = {};
  const ushort* Ag = A  + (size_t)m0*512;
  const ushort* Bg = WT + (size_t)n0*512;
  const int srow = lane>>3, sphys = lane&7;
  for (int k0=0;k0<512;k0+=64){
#pragma unroll
    for (int tt=0;tt<4;tt++){
      int r = tt*32 + w*8 + srow;
      int lc = sphys ^ (r&7);
      __builtin_amdgcn_global_load_lds(AS1C(Bg + (size_t)r*512 + k0 + lc*8), AS3(Bl + (tt*32+w*8)*64), 16, 0, 0);
      if (tt < 2)
        __builtin_amdgcn_global_load_lds(AS1C(Ag + (size_t)r*512 + k0 + lc*8), AS3(Al + (tt*32+w*8)*64), 16, 0, 0);
    }
    __syncthreads();
    const int mh = (w>>1)*32, nh = (w&1)*64;
#pragma unroll
    for (int kk=0;kk<2;kk++){
      bf16x8 af[2], bf[4];
#pragma unroll
      for (int mt=0;mt<2;mt++){
        int r = mh + mt*16 + (lane&15);
        int pc = (kk*4 + (lane>>4)) ^ (r&7);
        af[mt] = *(const bf16x8*)(Al + r*64 + pc*8);
      }
#pragma unroll
      for (int nt=0;nt<4;nt++){
        int r = nh + nt*16 + (lane&15);
        int pc = (kk*4 + (lane>>4)) ^ (r&7);
        bf[nt] = *(const bf16x8*)(Bl + r*64 + pc*8);
      }
#pragma unroll
      for (int mt=0;mt<2;mt++)
#pragma unroll
        for (int nt=0;nt<4;nt++)
          acc[mt][nt] = __builtin_amdgcn_mfma_f32_16x16x32_bf16(af[mt], bf[nt], acc[mt][nt], 0,0,0);
    }
    __syncthreads();
  }
  const int c = lane&15;
  const int rbase = m0 + (w>>1)*32 + (lane>>4)*4;
  const int cb = n0 + (w&1)*64;
#pragma unroll
  for (int mt=0;mt<2;mt++)
#pragma unroll
    for (int nt=0;nt<4;nt++)
#pragma unroll
      for (int reg=0;reg<4;reg++){
        int rg = rbase + mt*16 + reg;
        size_t idx = (size_t)rg*512 + cb + nt*16 + c;
        float v = acc[mt][nt][reg];
        if (isf) ((float*)Out)[idx] = v;
        else     ((ushort*)Out)[idx] = f2b(v);
      }
}

// ---------------- launcher ----------------
extern "C" void kernel_launch(void* const* d_in, const int* in_sizes, int n_in,
                              void* d_out, int out_size, void* d_ws, size_t ws_size,
                              hipStream_t stream){
  const void* x    = d_in[0];   // [2,4096,512]
  const void* Wqkv = d_in[1];   // [512,1536]
  const void* Wout = d_in[2];   // [512,512]
  // d_in[3] = attention_mask (causal by construction; applied analytically)
  char* ws = (char*)d_ws;
  float*  Lpart = (float*) (ws + 4096);          //   524,288
  ushort* WqkvT = (ushort*)(ws + 1052672);       // 1,572,864
  ushort* WoutT = (ushort*)(ws + 2625536);       //   524,288
  ushort* xb    = (ushort*)(ws + 3149824);       // 8,388,608  (reused as Opart after qkv_rope)
  ushort* Qw    = (ushort*)(ws + 11538432);      // 8,388,608
  ushort* Kw    = (ushort*)(ws + 19927040);      // 8,388,608
  ushort* Vw    = (ushort*)(ws + 28315648);      // 8,388,608 (transposed per head)
  ushort* Ow    = (ushort*)(ws + 36704256);      // 8,388,608 -> total 45,092,864 B
  ushort* Opart = xb;

  prep     <<<dim3(3072),  dim3(256), 0, stream>>>(x, xb, Wqkv, WqkvT, Wout, WoutT);
  qkv_rope <<<dim3(12,64), dim3(256), 0, stream>>>(xb, WqkvT, Qw, Kw, Vw);
  flash_attn<<<dim3(768),  dim3(256), 0, stream>>>(Qw, Kw, Vw, Ow, Opart, Lpart);
  combine  <<<dim3(16,16), dim3(256), 0, stream>>>(Opart, Lpart, Ow);
  out_proj <<<dim3(4,128), dim3(256), 0, stream>>>(Ow, WoutT, d_out, (const ushort*)x);
}